// Round 17
// baseline (402.321 us; speedup 1.0000x reference)
//
#include <hip/hip_runtime.h>
#include <hip/hip_bf16.h>
#include <math.h>

// ---- problem constants ----
#define NB    4          // batch
#define LSEQ  8192       // H*W
#define HH    64
#define WW    128
#define DMODEL 256
#define DINNER 512
#define NH    8          // heads
#define DSTATE 64
#define DPROJ 1160       // 2*512 + 2*64 + 8
#define CONVD 640        // 512 + 128
#define MROWS (NB*LSEQ)  // 32768
#define KVCH  32         // l-chunks per (b,h) in kv_part
#define CBLK  80         // 640/8 channel-blocks per position

typedef unsigned short bf16_t;
typedef __attribute__((ext_vector_type(8))) unsigned short ushort8v;
typedef __attribute__((ext_vector_type(8))) short short8v;   // MFMA A/B frag (8 bf16)
typedef __attribute__((ext_vector_type(4))) float f32x4;     // MFMA C/D frag

static __device__ __forceinline__ float bf2f(bf16_t u) {
    return __uint_as_float(((unsigned)u) << 16);
}
static __device__ __forceinline__ bf16_t f2bf(float f) {
    unsigned u = __float_as_uint(f);
    u += 0x7FFFu + ((u >> 16) & 1u);   // round-nearest-even
    return (bf16_t)(u >> 16);
}

// =====================================================================
// Weight pack: f32 [N][K] -> fragment-major bf16 Bp[nb][kt][512 slots][8]
// =====================================================================
__global__ __launch_bounds__(256) void wpad_frag_kernel(
    const float* __restrict__ W, bf16_t* __restrict__ Bp,
    int N, int K, int ntile)
{
    const int KT = K >> 5;
    const int i = blockIdx.x * 256 + threadIdx.x;
    if (i >= ntile * KT * 4096) return;
    const int j  = i & 7;
    const int L  = (i >> 3) & 511;
    const int kt = (i >> 12) % KT;          // KT is 8 or 16 (pow2)
    const int nb = i / (KT * 4096);
    const int rt = ((L >> 8) << 6) + (((L >> 6) & 3) << 4) + ((L >> 2) & 15);
    const int r  = nb * 128 + rt;
    const int c  = kt * 32 + (L & 3) * 8 + j;
    Bp[i] = (r < N) ? f2bf(W[(size_t)r * K + c]) : (bf16_t)0;
}

// =====================================================================
// MFMA GEMM, 512 thr = 8 waves (4M x 2N), 256x128 tile, BK=32.
// A: LDS double-buffer, fragment-major (r13-proven).
// B: fragment-major packed global (L2), REGISTER double-buffered --
// bnext for tile t+1 is issued BEFORE tile t's MFMAs, so L2 latency
// hides under ~614 cyc of MFMA (r16's exposed-latency fix).
// =====================================================================
template <typename TC>
__global__ __launch_bounds__(512) void gemm_mfma_big(
    const bf16_t* __restrict__ A, int lda,
    const bf16_t* __restrict__ Bp,     // packed [nb][kt][4096]
    TC* __restrict__ C, int ldc,
    int M, int N, int K)
{
    __shared__ __align__(16) bf16_t As[2][256 * 32];   // 16KB x2 (A only)
    const int nwg = gridDim.x * gridDim.y;
    const int wg  = blockIdx.y * gridDim.x + blockIdx.x;
    const int swz = (wg & 7) * (nwg >> 3) + (wg >> 3);
    const int bx  = swz % gridDim.x;
    const int by  = swz / gridDim.x;

    const int tid = threadIdx.x;
    const int m0 = by * 256;
    const int n0 = bx * 128;
    const int w    = tid >> 6;
    const int lane = tid & 63;
    const int wrow = w >> 1;          // 0..3 (64-row band)
    const int wcol = w & 1;           // 0..1 (64-col band)
    const int fr = lane & 15;
    const int kq = lane >> 4;         // 0..3

    f32x4 acc[4][4];
    #pragma unroll
    for (int i = 0; i < 4; ++i)
        #pragma unroll
        for (int j = 0; j < 4; ++j) acc[i][j] = (f32x4){0.f, 0.f, 0.f, 0.f};

    // fragment-major A staging decode (r13-verified):
    int arow[2], acol[2];
    #pragma unroll
    for (int i = 0; i < 2; ++i) {
        const int L = i * 512 + tid;          // A slots 0..1023
        arow[i] = ((L >> 8) << 6) + (((L >> 6) & 3) << 4) + ((L >> 2) & 15);
        acol[i] = (L & 3) * 8;
    }

#define STAGE_A(buf, k0)                                                       \
    {                                                                          \
        _Pragma("unroll")                                                      \
        for (int i = 0; i < 2; ++i) {                                          \
            const size_t ga = (size_t)(m0 + arow[i]) * lda + (k0) + acol[i];   \
            __builtin_amdgcn_global_load_lds(                                  \
                (const __attribute__((address_space(1))) void*)(A + ga),       \
                (__attribute__((address_space(3))) void*)(&As[buf][(i * 512 + tid) * 8]), 16, 0, 0); \
        }                                                                      \
    }

    const int nt = K >> 5;
    const bf16_t* Bpt = Bp + (size_t)bx * nt * 4096;    // this n-tile's pack
    const int boff = wcol * 2048 + (fr * 4 + kq) * 8;   // elem offset in kt-tile

    STAGE_A(0, 0);

    // prologue B prefetch (tile 0)
    short8v bcur[4], bnext[4];
    #pragma unroll
    for (int n = 0; n < 4; ++n)
        bnext[n] = *(const short8v*)&Bpt[boff + n * 512];

    __syncthreads();                       // drain A prologue staging

    const int abase = wrow * 2048 + (fr * 4 + kq) * 8;   // elem offset

    int cur = 0;
    for (int t = 0; t < nt; ++t) {
        if (t + 1 < nt) STAGE_A(cur ^ 1, (t + 1) * 32);   // prefetch next A

        // rotate B regs; issue next-tile B loads BEFORE this tile's MFMAs
        #pragma unroll
        for (int n = 0; n < 4; ++n) bcur[n] = bnext[n];
        if (t + 1 < nt) {
            #pragma unroll
            for (int n = 0; n < 4; ++n)
                bnext[n] = *(const short8v*)&Bpt[(size_t)(t + 1) * 4096 + boff + n * 512];
        }

        short8v a_frag[4];
        #pragma unroll
        for (int m = 0; m < 4; ++m)
            a_frag[m] = *(const short8v*)&As[cur][abase + m * 512];
        #pragma unroll
        for (int m = 0; m < 4; ++m)
            #pragma unroll
            for (int n = 0; n < 4; ++n)
                acc[m][n] = __builtin_amdgcn_mfma_f32_16x16x32_bf16(
                    a_frag[m], bcur[n], acc[m][n], 0, 0, 0);

        __syncthreads();   // drains A prefetch + guards buffer reuse
        cur ^= 1;
    }
#undef STAGE_A

    #pragma unroll
    for (int mi = 0; mi < 4; ++mi) {
        #pragma unroll
        for (int ni = 0; ni < 4; ++ni) {
            const int col = n0 + wcol * 64 + ni * 16 + fr;
            if (col < N) {
                #pragma unroll
                for (int q = 0; q < 4; ++q) {
                    const int row = m0 + wrow * 64 + mi * 16 + kq * 4 + q;
                    if constexpr (sizeof(TC) == 2)
                        C[(size_t)row * ldc + col] = f2bf(acc[mi][ni][q]);
                    else
                        C[(size_t)row * ldc + col] = acc[mi][ni][q];
                }
            }
        }
    }
}

// =====================================================================
// MFMA GEMM (m97 recipe, BK=32, batch strides) — ymm (K=64) + out-proj.
// =====================================================================
template <typename TC>
__global__ __launch_bounds__(256) void gemm_mfma_bt(
    const bf16_t* __restrict__ A, int lda, size_t sAb,
    const bf16_t* __restrict__ B, int ldb, size_t sBb,
    TC* __restrict__ C, int ldc, size_t sCb,
    int M, int N, int K)
{
    __shared__ __align__(16) bf16_t As[128 * 32];
    __shared__ __align__(16) bf16_t Bs[128 * 32];
    const bf16_t* Ab = A + blockIdx.z * sAb;
    const bf16_t* Bb = B + blockIdx.z * sBb;
    TC*            Cb = C + blockIdx.z * sCb;
    const int tid = threadIdx.x;
    const int m0 = blockIdx.y * 128;
    const int n0 = blockIdx.x * 128;
    const int wid = tid >> 6;
    const int lane = tid & 63;
    const int wr = (wid >> 1) * 64;
    const int wc = (wid & 1) * 64;
    const int fr = lane & 15;
    const int fk = (lane >> 4) * 8;

    f32x4 acc[4][4];
    #pragma unroll
    for (int i = 0; i < 4; ++i)
        #pragma unroll
        for (int j = 0; j < 4; ++j) acc[i][j] = (f32x4){0.f, 0.f, 0.f, 0.f};

    const int srow = tid >> 2;
    const int scol = (tid & 3) * 8;
    const bf16_t* gA = Ab + (size_t)(m0 + srow) * lda + scol;
    const bf16_t* gB = Bb + (size_t)(n0 + srow) * ldb + scol;
    bf16_t* lA = As + tid * 8;
    bf16_t* lB = Bs + tid * 8;

    for (int k0 = 0; k0 < K; k0 += 32) {
        __builtin_amdgcn_global_load_lds(
            (const __attribute__((address_space(1))) void*)(gA + k0),
            (__attribute__((address_space(3))) void*)lA, 16, 0, 0);
        __builtin_amdgcn_global_load_lds(
            (const __attribute__((address_space(1))) void*)(gA + (size_t)64 * lda + k0),
            (__attribute__((address_space(3))) void*)(lA + 2048), 16, 0, 0);
        __builtin_amdgcn_global_load_lds(
            (const __attribute__((address_space(1))) void*)(gB + k0),
            (__attribute__((address_space(3))) void*)lB, 16, 0, 0);
        __builtin_amdgcn_global_load_lds(
            (const __attribute__((address_space(1))) void*)(gB + (size_t)64 * ldb + k0),
            (__attribute__((address_space(3))) void*)(lB + 2048), 16, 0, 0);
        __syncthreads();

        short8v a_frag[4], b_frag[4];
        #pragma unroll
        for (int m = 0; m < 4; ++m)
            a_frag[m] = *(const short8v*)&As[(wr + m * 16 + fr) * 32 + fk];
        #pragma unroll
        for (int n = 0; n < 4; ++n)
            b_frag[n] = *(const short8v*)&Bs[(wc + n * 16 + fr) * 32 + fk];
        #pragma unroll
        for (int m = 0; m < 4; ++m)
            #pragma unroll
            for (int n = 0; n < 4; ++n)
                acc[m][n] = __builtin_amdgcn_mfma_f32_16x16x32_bf16(
                    a_frag[m], b_frag[n], acc[m][n], 0, 0, 0);
        __syncthreads();
    }

    #pragma unroll
    for (int mi = 0; mi < 4; ++mi) {
        #pragma unroll
        for (int ni = 0; ni < 4; ++ni) {
            const int col = n0 + wc + ni * 16 + fr;
            if (col < N) {
                #pragma unroll
                for (int q = 0; q < 4; ++q) {
                    const int row = m0 + wr + mi * 16 + (lane >> 4) * 4 + q;
                    if constexpr (sizeof(TC) == 2)
                        Cb[(size_t)row * ldc + col] = f2bf(acc[mi][ni][q]);
                    else
                        Cb[(size_t)row * ldc + col] = acc[mi][ni][q];
                }
            }
        }
    }
}

// =====================================================================
__global__ __launch_bounds__(256) void cvt_bf16_kernel(
    const float* __restrict__ in, bf16_t* __restrict__ out, int n)
{
    const int base = (blockIdx.x * 256 + threadIdx.x) * 4;
    if (base >= n) return;
    float4 v = *(const float4*)&in[base];
    ushort4 o;
    o.x = f2bf(v.x); o.y = f2bf(v.y); o.z = f2bf(v.z); o.w = f2bf(v.w);
    *(ushort4*)&out[base] = o;
}

__global__ __launch_bounds__(256) void wpad_kernel(
    const float* __restrict__ W, bf16_t* __restrict__ Wp,
    int N, int Npad, int K)
{
    const int i = blockIdx.x * 256 + threadIdx.x;
    if (i >= Npad * K) return;
    const int r = i / K, k = i - r * K;
    Wp[i] = (r < N) ? f2bf(W[(size_t)r * K + k]) : (bf16_t)0;
}

// =====================================================================
// 3x3 depthwise conv + bias + SiLU, channel-vectorized x8,
// 4 vertically-stacked outputs per thread (proven: VGPR 56, ~30us).
// =====================================================================
__global__ __launch_bounds__(256) void conv_silu_kernel(
    const bf16_t* __restrict__ zx,
    const float* __restrict__ wA, const float* __restrict__ bA,
    const float* __restrict__ wB, const float* __restrict__ bB,
    bf16_t* __restrict__ out)
{
    const int idx = blockIdx.x * 256 + threadIdx.x;   // < 8192*80
    const int cb = idx % CBLK;
    const int pc = idx / CBLK;         // (b,h4,w) column id, < 8192
    const int c0 = cb * 8;
    const int ww = pc & (WW - 1);
    const int h4 = (pc >> 7) & 15;
    const int b  = pc >> 11;
    const int hbase = h4 * 4;
    const float* wp = (b < 2) ? wA : wB;
    const float* bp = (b < 2) ? bA : bB;

    float w[72];
    const float4* wsrc = (const float4*)(wp + c0 * 9);
    #pragma unroll
    for (int i = 0; i < 18; ++i) ((float4*)w)[i] = wsrc[i];

    float acc[4][8];
    {
        float4 bv0 = *(const float4*)(bp + c0);
        float4 bv1 = *(const float4*)(bp + c0 + 4);
        #pragma unroll
        for (int o = 0; o < 4; ++o) {
            acc[o][0] = bv0.x; acc[o][1] = bv0.y; acc[o][2] = bv0.z; acc[o][3] = bv0.w;
            acc[o][4] = bv1.x; acc[o][5] = bv1.y; acc[o][6] = bv1.z; acc[o][7] = bv1.w;
        }
    }

    const bf16_t* base = zx + (size_t)b * LSEQ * DPROJ + DINNER + c0;
    #pragma unroll
    for (int ri = 0; ri < 6; ++ri) {           // input rows hbase-1 .. hbase+4
        const int hi = hbase + ri - 1;
        const bool hok = (unsigned)hi < (unsigned)HH;
        float cur[3][8];
        #pragma unroll
        for (int kj = 0; kj < 3; ++kj) {
            const int wi = ww + kj - 1;
            if (hok && (unsigned)wi < (unsigned)WW) {
                const ushort8v v = *(const ushort8v*)(base + (size_t)(hi * WW + wi) * DPROJ);
                #pragma unroll
                for (int q = 0; q < 8; ++q) cur[kj][q] = bf2f(v[q]);
            } else {
                #pragma unroll
                for (int q = 0; q < 8; ++q) cur[kj][q] = 0.f;
            }
        }
        #pragma unroll
        for (int o = 0; o < 4; ++o) {
            const int ki = ri - o;             // tap row for output o
            if (ki >= 0 && ki < 3) {
                #pragma unroll
                for (int kj = 0; kj < 3; ++kj)
                    #pragma unroll
                    for (int q = 0; q < 8; ++q)
                        acc[o][q] += cur[kj][q] * w[q * 9 + ki * 3 + kj];
            }
        }
    }

    #pragma unroll
    for (int o = 0; o < 4; ++o) {
        const int t = b * LSEQ + (hbase + o) * WW + ww;
        ushort8v ov;
        #pragma unroll
        for (int q = 0; q < 8; ++q) {
            const float s = acc[o][q] / (1.f + expf(-acc[o][q]));   // silu
            ov[q] = f2bf(s);
        }
        *(ushort8v*)(out + (size_t)t * CONVD + c0) = ov;
    }
}

// =====================================================================
// KV partials (dt fused): KVp[chunk][(b*8+h)*4096 + s*64 + p]
// =====================================================================
__global__ __launch_bounds__(128) void kv_part_kernel(
    const bf16_t* __restrict__ xconv, const bf16_t* __restrict__ zx,
    const float* __restrict__ dt_bias,
    const float* __restrict__ A_log, float* __restrict__ KVp)
{
    const int h = blockIdx.y, b = blockIdx.z, chunk = blockIdx.x;
    const int tid = threadIdx.x;
    const int w = tid >> 6, lane = tid & 63;
    __shared__ float lds[2 * 4352];
    float* Bt = lds + w * 4352;
    float* Xt = Bt + 2176;
    const float eA = expf(A_log[h]);
    const float dtb = dt_bias[h];
    const int s4  = (lane & 15) * 4;
    const int p16 = (lane >> 4) * 16;
    const int r    = lane & 31;
    const int part = lane >> 5;

    float acc[4][16];
    #pragma unroll
    for (int i = 0; i < 4; ++i)
        #pragma unroll
        for (int j = 0; j < 16; ++j) acc[i][j] = 0.f;

    const int l0 = b * LSEQ + chunk * 256;

    for (int t = 0; t < 8; t += 2) {
        const int row = l0 + (t + w) * 32 + r;
        const bf16_t* src = xconv + (size_t)row * CONVD + (part ? h * 64 : DINNER);
        float scale = 1.f;
        if (part) {
            const float v = bf2f(zx[(size_t)row * DPROJ + (DINNER + CONVD) + h]) + dtb;
            const float sp = (v > 0.f) ? (v + log1pf(expf(-v))) : log1pf(expf(v));
            scale = sp * eA;
        }
        float* dst = part ? &Xt[r * 68] : &Bt[r * 68];
        #pragma unroll
        for (int j = 0; j < 8; ++j) {
            ushort8v v = *(const ushort8v*)(src + j * 8);
            f32x4 lo = {bf2f(v[0]) * scale, bf2f(v[1]) * scale,
                        bf2f(v[2]) * scale, bf2f(v[3]) * scale};
            f32x4 hi = {bf2f(v[4]) * scale, bf2f(v[5]) * scale,
                        bf2f(v[6]) * scale, bf2f(v[7]) * scale};
            *(f32x4*)&dst[j * 8]     = lo;
            *(f32x4*)&dst[j * 8 + 4] = hi;
        }
        __syncthreads();
        #pragma unroll 4
        for (int rr = 0; rr < 32; ++rr) {
            const f32x4 bv = *(const f32x4*)&Bt[rr * 68 + s4];
            #pragma unroll
            for (int q = 0; q < 4; ++q) {
                const f32x4 xv = *(const f32x4*)&Xt[rr * 68 + p16 + q * 4];
                #pragma unroll
                for (int si = 0; si < 4; ++si)
                    #pragma unroll
                    for (int k = 0; k < 4; ++k)
                        acc[si][q * 4 + k] += bv[si] * xv[k];
            }
        }
        __syncthreads();
    }

    if (w == 0) {
        #pragma unroll
        for (int si = 0; si < 4; ++si)
            #pragma unroll
            for (int q = 0; q < 4; ++q)
                *(f32x4*)&lds[(s4 + si) * 68 + p16 + q * 4] =
                    (f32x4){acc[si][q*4], acc[si][q*4+1], acc[si][q*4+2], acc[si][q*4+3]};
    }
    __syncthreads();
    if (w == 1) {
        float* dst = KVp + ((size_t)chunk * (NB * NH) + (b * NH + h)) * 4096;
        #pragma unroll
        for (int si = 0; si < 4; ++si)
            #pragma unroll
            for (int q = 0; q < 4; ++q) {
                const f32x4 o = *(const f32x4*)&lds[(s4 + si) * 68 + p16 + q * 4];
                f32x4 v = {acc[si][q*4] + o[0], acc[si][q*4+1] + o[1],
                           acc[si][q*4+2] + o[2], acc[si][q*4+3] + o[3]};
                *(f32x4*)&dst[(s4 + si) * 64 + p16 + q * 4] = v;
            }
    }
}

// =====================================================================
// KVT[b][h*64+p][s] (bf16) = sum_chunk KVp[chunk][(b*8+h)*4096+s*64+p]
// =====================================================================
__global__ __launch_bounds__(256) void kv_reduce_T_kernel(
    const float* __restrict__ KVp, bf16_t* __restrict__ KVT)
{
    const int idx = blockIdx.x * 256 + threadIdx.x;   // < 131072
    float s = 0.f;
    #pragma unroll
    for (int c = 0; c < KVCH; ++c) s += KVp[(size_t)c * 131072 + idx];
    const int bh = idx >> 12;          // b*8+h
    const int ss = (idx >> 6) & 63;
    const int p  = idx & 63;
    KVT[((size_t)(bh * 64 + p)) * 64 + ss] = f2bf(s);
}

// =====================================================================
// LN + gate: y = Yattn + x*Dv -> LayerNorm(512) -> *g+b -> *z -> ybuf
// =====================================================================
__global__ __launch_bounds__(256) void ln_gate_kernel(
    const bf16_t* __restrict__ Yattn, const bf16_t* __restrict__ xconv,
    const bf16_t* __restrict__ zx,
    const float* __restrict__ DA, const float* __restrict__ DB,
    const float* __restrict__ ln_g, const float* __restrict__ ln_b,
    bf16_t* __restrict__ ybuf)
{
    const int w = threadIdx.x >> 6, lane = threadIdx.x & 63;
    const int c0 = lane * 8;
    const int h = lane >> 3;
    float g[8], be[8];
    *(float4*)&g[0]  = *(const float4*)&ln_g[c0];
    *(float4*)&g[4]  = *(const float4*)&ln_g[c0 + 4];
    *(float4*)&be[0] = *(const float4*)&ln_b[c0];
    *(float4*)&be[4] = *(const float4*)&ln_b[c0 + 4];
    const int row0 = (blockIdx.x * 4 + w) * 4;

    for (int i = 0; i < 4; ++i) {
        const int row = row0 + i;
        const int b = row >> 13;
        const float Dv = (b < 2) ? DA[h] : DB[h];
        ushort8v yv = *(const ushort8v*)(Yattn + (size_t)row * DINNER + c0);
        ushort8v xv = *(const ushort8v*)(xconv + (size_t)row * CONVD + c0);
        float y[8];
        float s1 = 0.f, s2 = 0.f;
        #pragma unroll
        for (int q = 0; q < 8; ++q) {
            y[q] = bf2f(yv[q]) + bf2f(xv[q]) * Dv;
            s1 += y[q]; s2 += y[q] * y[q];
        }
        #pragma unroll
        for (int off = 32; off > 0; off >>= 1) {
            s1 += __shfl_xor(s1, off, 64);
            s2 += __shfl_xor(s2, off, 64);
        }
        const float mu = s1 * (1.f / 512.f);
        const float var = s2 * (1.f / 512.f) - mu * mu;
        const float rstd = rsqrtf(var + 1e-5f);
        ushort8v zv = *(const ushort8v*)(zx + (size_t)row * DPROJ + c0);
        ushort8v o;
        #pragma unroll
        for (int q = 0; q < 8; ++q)
            o[q] = f2bf(((y[q] - mu) * rstd * g[q] + be[q]) * bf2f(zv[q]));
        *(ushort8v*)(ybuf + (size_t)row * DINNER + c0) = o;
    }
}

// =====================================================================
extern "C" void kernel_launch(void* const* d_in, const int* in_sizes, int n_in,
                              void* d_out, int out_size, void* d_ws, size_t ws_size,
                              hipStream_t stream)
{
    const float* u        = (const float*)d_in[0];
    const float* W_in     = (const float*)d_in[3];
    const float* W_st     = (const float*)d_in[4];
    const float* conv_l_w = (const float*)d_in[5];
    const float* conv_l_b = (const float*)d_in[6];
    const float* conv_r_w = (const float*)d_in[7];
    const float* conv_r_b = (const float*)d_in[8];
    const float* conv_w   = (const float*)d_in[9];
    const float* conv_b   = (const float*)d_in[10];
    const float* dt_bias  = (const float*)d_in[11];
    const float* A_log    = (const float*)d_in[12];
    const float* D_l      = (const float*)d_in[13];
    const float* D_r      = (const float*)d_in[14];
    const float* Dp       = (const float*)d_in[15];
    const float* ln_g     = (const float*)d_in[16];
    const float* ln_b     = (const float*)d_in[17];
    const float* W_out    = (const float*)d_in[18];
    float* out = (float*)d_out;

    // ---- workspace layout: ~205 MB (KVp aliases ubf; KVT bf16; Yattn bf16) ----
    char* ws = (char*)d_ws;
    const size_t ZX_B    = (size_t)MROWS * DPROJ * 2;    //  76,021,760
    const size_t XCONV_B = (size_t)MROWS * CONVD * 2;    //  41,943,040
    const size_t YBUF_B  = (size_t)MROWS * DINNER * 2;   //  33,554,432
    const size_t DT_B    = (size_t)MROWS * NH * 4;       //   1,048,576 (unused; layout stability)
    const size_t KVT_B   = (size_t)NB * DINNER * 64 * 2; //     262,144
    const size_t UBF_B   = (size_t)MROWS * DMODEL * 2;   //  16,777,216 (== KVCH*131072*4)
    const size_t WIN_B   = (size_t)1280 * DMODEL * 2;    //  WinF (frag-packed)
    const size_t WST_B   = (size_t)1280 * DINNER * 2;    //  WstF (frag-packed)
    const size_t WOUT_B  = (size_t)256 * DINNER * 2;
    bf16_t* zx    = (bf16_t*)(ws);
    bf16_t* xconv = (bf16_t*)(ws + ZX_B);
    bf16_t* ybuf  = (bf16_t*)(ws + ZX_B + XCONV_B);
    bf16_t* KVT   = (bf16_t*)(ws + ZX_B + XCONV_B + YBUF_B + DT_B);
    bf16_t* ubf   = (bf16_t*)(ws + ZX_B + XCONV_B + YBUF_B + DT_B + KVT_B);
    float*  KVp   = (float*) (ws + ZX_B + XCONV_B + YBUF_B + DT_B + KVT_B);  // alias (ubf dead after gemm1)
    bf16_t* WinF  = (bf16_t*)(ws + ZX_B + XCONV_B + YBUF_B + DT_B + KVT_B + UBF_B);
    bf16_t* WstF  = (bf16_t*)(ws + ZX_B + XCONV_B + YBUF_B + DT_B + KVT_B + UBF_B + WIN_B);
    bf16_t* WoutP = (bf16_t*)(ws + ZX_B + XCONV_B + YBUF_B + DT_B + KVT_B + UBF_B + WIN_B + WST_B);
    bf16_t* Yattn = (bf16_t*)(ws + ZX_B + XCONV_B + YBUF_B + DT_B + KVT_B + UBF_B + WIN_B + WST_B + WOUT_B);

    const dim3 gemmGridP(10, MROWS / 256);        // Npad=1280, 1280 blocks (%8==0)
    const dim3 gemmGridO(2,  MROWS / 128, 1);     // out-proj on bt: 512 blocks
    const dim3 ymmGrid(4, LSEQ / 128, NB);        // N=512, per-batch
    const dim3 kvGrid(KVCH, NH, NB);
    const int convGrid = (MROWS / 4) * CBLK / 256; // 2560
    const int lnGrid = MROWS / 16;                 // 2048

    // ---- one-time conversions ----
    cvt_bf16_kernel<<<(MROWS * DMODEL / 4 + 255) / 256, 256, 0, stream>>>(u, ubf, MROWS * DMODEL);
    wpad_frag_kernel<<<(10 * 8  * 4096) / 256, 256, 0, stream>>>(W_in, WinF, DPROJ, DMODEL, 10);
    wpad_frag_kernel<<<(10 * 16 * 4096) / 256, 256, 0, stream>>>(W_st, WstF, DPROJ, DINNER, 10);
    wpad_kernel<<<(256 * DINNER + 255) / 256, 256, 0, stream>>>(W_out, WoutP, DMODEL, 256, DINNER);

    // ---------------- pass 1 ----------------
    gemm_mfma_big<bf16_t><<<gemmGridP, 512, 0, stream>>>(
        ubf, DMODEL, WinF, zx, DPROJ, MROWS, DPROJ, DMODEL);
    conv_silu_kernel<<<convGrid, 256, 0, stream>>>(
        zx, conv_l_w, conv_l_b, conv_r_w, conv_r_b, xconv);
    kv_part_kernel<<<kvGrid, 128, 0, stream>>>(xconv, zx, dt_bias, A_log, KVp);
    kv_reduce_T_kernel<<<131072 / 256, 256, 0, stream>>>(KVp, KVT);
    gemm_mfma_bt<bf16_t><<<ymmGrid, 256, 0, stream>>>(
        xconv + DINNER + DSTATE, CONVD, (size_t)LSEQ * CONVD,
        KVT, 64, (size_t)DINNER * 64,
        Yattn, DINNER, (size_t)LSEQ * DINNER, LSEQ, DINNER, 64);
    ln_gate_kernel<<<lnGrid, 256, 0, stream>>>(
        Yattn, xconv, zx, D_l, D_r, ln_g, ln_b, ybuf);

    // ---------------- pass 2 ----------------
    gemm_mfma_big<bf16_t><<<gemmGridP, 512, 0, stream>>>(
        ybuf, DINNER, WstF, zx, DPROJ, MROWS, DPROJ, DINNER);
    conv_silu_kernel<<<convGrid, 256, 0, stream>>>(
        zx, conv_w, conv_b, conv_w, conv_b, xconv);
    kv_part_kernel<<<kvGrid, 128, 0, stream>>>(xconv, zx, dt_bias, A_log, KVp);
    kv_reduce_T_kernel<<<131072 / 256, 256, 0, stream>>>(KVp, KVT);
    gemm_mfma_bt<bf16_t><<<ymmGrid, 256, 0, stream>>>(
        xconv + DINNER + DSTATE, CONVD, (size_t)LSEQ * CONVD,
        KVT, 64, (size_t)DINNER * 64,
        Yattn, DINNER, (size_t)LSEQ * DINNER, LSEQ, DINNER, 64);
    ln_gate_kernel<<<lnGrid, 256, 0, stream>>>(
        Yattn, xconv, zx, Dp, Dp, ln_g, ln_b, ybuf);

    // ---------------- output projection (128-tile bt: 512 blocks) ----------------
    gemm_mfma_bt<float><<<gemmGridO, 256, 0, stream>>>(
        ybuf, DINNER, 0, WoutP, DINNER, 0, out, DMODEL, 0, MROWS, DMODEL, DINNER);
}

// Round 18
// 384.878 us; speedup vs baseline: 1.0453x; 1.0453x over previous
//
#include <hip/hip_runtime.h>
#include <hip/hip_bf16.h>
#include <math.h>

// ---- problem constants ----
#define NB    4          // batch
#define LSEQ  8192       // H*W
#define HH    64
#define WW    128
#define DMODEL 256
#define DINNER 512
#define NH    8          // heads
#define DSTATE 64
#define DPROJ 1160       // 2*512 + 2*64 + 8
#define CONVD 640        // 512 + 128
#define MROWS (NB*LSEQ)  // 32768
#define KVCH  32         // l-chunks per (b,h) in kv_part
#define CBLK  80         // 640/8 channel-blocks per position

typedef unsigned short bf16_t;
typedef __attribute__((ext_vector_type(8))) unsigned short ushort8v;
typedef __attribute__((ext_vector_type(8))) short short8v;   // MFMA A/B frag (8 bf16)
typedef __attribute__((ext_vector_type(4))) float f32x4;     // MFMA C/D frag

static __device__ __forceinline__ float bf2f(bf16_t u) {
    return __uint_as_float(((unsigned)u) << 16);
}
static __device__ __forceinline__ bf16_t f2bf(float f) {
    unsigned u = __float_as_uint(f);
    u += 0x7FFFu + ((u >> 16) & 1u);   // round-nearest-even
    return (bf16_t)(u >> 16);
}

// =====================================================================
// MFMA GEMM, 512 thr = 8 waves (4M x 2N), 256x128 tile, BK=32,
// 2-phase double-buffer, fragment-major LDS (measured-best r15 config;
// B-from-L2 variants (r16/r17) both regressed 64->79us: reverted).
// =====================================================================
template <typename TC>
__global__ __launch_bounds__(512) void gemm_mfma_big(
    const bf16_t* __restrict__ A, int lda,
    const bf16_t* __restrict__ B, int ldb,
    TC* __restrict__ C, int ldc,
    int M, int N, int K)
{
    __shared__ __align__(16) bf16_t As[2][256 * 32];   // 16KB x2
    __shared__ __align__(16) bf16_t Bs[2][128 * 32];   //  8KB x2
    const int nwg = gridDim.x * gridDim.y;
    const int wg  = blockIdx.y * gridDim.x + blockIdx.x;
    const int swz = (wg & 7) * (nwg >> 3) + (wg >> 3);
    const int bx  = swz % gridDim.x;
    const int by  = swz / gridDim.x;

    const int tid = threadIdx.x;
    const int m0 = by * 256;
    const int n0 = bx * 128;
    const int w    = tid >> 6;
    const int lane = tid & 63;
    const int wrow = w >> 1;          // 0..3 (64-row band)
    const int wcol = w & 1;           // 0..1 (64-col band)
    const int fr = lane & 15;
    const int kq = lane >> 4;         // 0..3

    f32x4 acc[4][4];
    #pragma unroll
    for (int i = 0; i < 4; ++i)
        #pragma unroll
        for (int j = 0; j < 4; ++j) acc[i][j] = (f32x4){0.f, 0.f, 0.f, 0.f};

    // fragment-major staging decode:
    // slot L -> row = (L>>8)*64 + ((L>>6)&3)*16 + ((L>>2)&15), col = (L&3)*8
    int arow[2], acol[2];
    #pragma unroll
    for (int i = 0; i < 2; ++i) {
        const int L = i * 512 + tid;          // A slots 0..1023
        arow[i] = ((L >> 8) << 6) + (((L >> 6) & 3) << 4) + ((L >> 2) & 15);
        acol[i] = (L & 3) * 8;
    }
    const int Lb = tid;                        // B slots 0..511
    const int brow = ((Lb >> 8) << 6) + (((Lb >> 6) & 3) << 4) + ((Lb >> 2) & 15);
    const int bcol = (Lb & 3) * 8;

#define STAGE_BIG(buf, k0)                                                     \
    {                                                                          \
        _Pragma("unroll")                                                      \
        for (int i = 0; i < 2; ++i) {                                          \
            const size_t ga = (size_t)(m0 + arow[i]) * lda + (k0) + acol[i];   \
            __builtin_amdgcn_global_load_lds(                                  \
                (const __attribute__((address_space(1))) void*)(A + ga),       \
                (__attribute__((address_space(3))) void*)(&As[buf][(i * 512 + tid) * 8]), 16, 0, 0); \
        }                                                                      \
        const size_t gb = (size_t)(n0 + brow) * ldb + (k0) + bcol;             \
        __builtin_amdgcn_global_load_lds(                                      \
            (const __attribute__((address_space(1))) void*)(B + gb),           \
            (__attribute__((address_space(3))) void*)(&Bs[buf][tid * 8]), 16, 0, 0); \
    }

    const int nt = K >> 5;
    STAGE_BIG(0, 0);
    __syncthreads();                       // drain prologue staging

    const int abase = wrow * 2048 + (fr * 4 + kq) * 8;   // elem offset
    const int bbase = wcol * 2048 + (fr * 4 + kq) * 8;

    int cur = 0;
    for (int t = 0; t < nt; ++t) {
        if (t + 1 < nt) STAGE_BIG(cur ^ 1, (t + 1) * 32);   // prefetch next

        short8v a_frag[4], b_frag[4];
        #pragma unroll
        for (int m = 0; m < 4; ++m)
            a_frag[m] = *(const short8v*)&As[cur][abase + m * 512];
        #pragma unroll
        for (int n = 0; n < 4; ++n)
            b_frag[n] = *(const short8v*)&Bs[cur][bbase + n * 512];
        #pragma unroll
        for (int m = 0; m < 4; ++m)
            #pragma unroll
            for (int n = 0; n < 4; ++n)
                acc[m][n] = __builtin_amdgcn_mfma_f32_16x16x32_bf16(
                    a_frag[m], b_frag[n], acc[m][n], 0, 0, 0);

        __syncthreads();   // drains prefetch vmcnt + guards buffer reuse
        cur ^= 1;
    }
#undef STAGE_BIG

    #pragma unroll
    for (int mi = 0; mi < 4; ++mi) {
        #pragma unroll
        for (int ni = 0; ni < 4; ++ni) {
            const int col = n0 + wcol * 64 + ni * 16 + fr;
            if (col < N) {
                #pragma unroll
                for (int q = 0; q < 4; ++q) {
                    const int row = m0 + wrow * 64 + mi * 16 + kq * 4 + q;
                    if constexpr (sizeof(TC) == 2)
                        C[(size_t)row * ldc + col] = f2bf(acc[mi][ni][q]);
                    else
                        C[(size_t)row * ldc + col] = acc[mi][ni][q];
                }
            }
        }
    }
}

// =====================================================================
// MFMA GEMM (m97 recipe, BK=32, batch strides) — ymm (K=64) + out-proj.
// =====================================================================
template <typename TC>
__global__ __launch_bounds__(256) void gemm_mfma_bt(
    const bf16_t* __restrict__ A, int lda, size_t sAb,
    const bf16_t* __restrict__ B, int ldb, size_t sBb,
    TC* __restrict__ C, int ldc, size_t sCb,
    int M, int N, int K)
{
    __shared__ __align__(16) bf16_t As[128 * 32];
    __shared__ __align__(16) bf16_t Bs[128 * 32];
    const bf16_t* Ab = A + blockIdx.z * sAb;
    const bf16_t* Bb = B + blockIdx.z * sBb;
    TC*            Cb = C + blockIdx.z * sCb;
    const int tid = threadIdx.x;
    const int m0 = blockIdx.y * 128;
    const int n0 = blockIdx.x * 128;
    const int wid = tid >> 6;
    const int lane = tid & 63;
    const int wr = (wid >> 1) * 64;
    const int wc = (wid & 1) * 64;
    const int fr = lane & 15;
    const int fk = (lane >> 4) * 8;

    f32x4 acc[4][4];
    #pragma unroll
    for (int i = 0; i < 4; ++i)
        #pragma unroll
        for (int j = 0; j < 4; ++j) acc[i][j] = (f32x4){0.f, 0.f, 0.f, 0.f};

    const int srow = tid >> 2;
    const int scol = (tid & 3) * 8;
    const bf16_t* gA = Ab + (size_t)(m0 + srow) * lda + scol;
    const bf16_t* gB = Bb + (size_t)(n0 + srow) * ldb + scol;
    bf16_t* lA = As + tid * 8;
    bf16_t* lB = Bs + tid * 8;

    for (int k0 = 0; k0 < K; k0 += 32) {
        __builtin_amdgcn_global_load_lds(
            (const __attribute__((address_space(1))) void*)(gA + k0),
            (__attribute__((address_space(3))) void*)lA, 16, 0, 0);
        __builtin_amdgcn_global_load_lds(
            (const __attribute__((address_space(1))) void*)(gA + (size_t)64 * lda + k0),
            (__attribute__((address_space(3))) void*)(lA + 2048), 16, 0, 0);
        __builtin_amdgcn_global_load_lds(
            (const __attribute__((address_space(1))) void*)(gB + k0),
            (__attribute__((address_space(3))) void*)lB, 16, 0, 0);
        __builtin_amdgcn_global_load_lds(
            (const __attribute__((address_space(1))) void*)(gB + (size_t)64 * ldb + k0),
            (__attribute__((address_space(3))) void*)(lB + 2048), 16, 0, 0);
        __syncthreads();

        short8v a_frag[4], b_frag[4];
        #pragma unroll
        for (int m = 0; m < 4; ++m)
            a_frag[m] = *(const short8v*)&As[(wr + m * 16 + fr) * 32 + fk];
        #pragma unroll
        for (int n = 0; n < 4; ++n)
            b_frag[n] = *(const short8v*)&Bs[(wc + n * 16 + fr) * 32 + fk];
        #pragma unroll
        for (int m = 0; m < 4; ++m)
            #pragma unroll
            for (int n = 0; n < 4; ++n)
                acc[m][n] = __builtin_amdgcn_mfma_f32_16x16x32_bf16(
                    a_frag[m], b_frag[n], acc[m][n], 0, 0, 0);
        __syncthreads();
    }

    #pragma unroll
    for (int mi = 0; mi < 4; ++mi) {
        #pragma unroll
        for (int ni = 0; ni < 4; ++ni) {
            const int col = n0 + wc + ni * 16 + fr;
            if (col < N) {
                #pragma unroll
                for (int q = 0; q < 4; ++q) {
                    const int row = m0 + wr + mi * 16 + (lane >> 4) * 4 + q;
                    if constexpr (sizeof(TC) == 2)
                        Cb[(size_t)row * ldc + col] = f2bf(acc[mi][ni][q]);
                    else
                        Cb[(size_t)row * ldc + col] = acc[mi][ni][q];
                }
            }
        }
    }
}

// =====================================================================
__global__ __launch_bounds__(256) void cvt_bf16_kernel(
    const float* __restrict__ in, bf16_t* __restrict__ out, int n)
{
    const int base = (blockIdx.x * 256 + threadIdx.x) * 4;
    if (base >= n) return;
    float4 v = *(const float4*)&in[base];
    ushort4 o;
    o.x = f2bf(v.x); o.y = f2bf(v.y); o.z = f2bf(v.z); o.w = f2bf(v.w);
    *(ushort4*)&out[base] = o;
}

__global__ __launch_bounds__(256) void wpad_kernel(
    const float* __restrict__ W, bf16_t* __restrict__ Wp,
    int N, int Npad, int K)
{
    const int i = blockIdx.x * 256 + threadIdx.x;
    if (i >= Npad * K) return;
    const int r = i / K, k = i - r * K;
    Wp[i] = (r < N) ? f2bf(W[(size_t)r * K + k]) : (bf16_t)0;
}

// =====================================================================
// 3x3 depthwise conv + bias + SiLU, channel-vectorized x8,
// 4 vertically-stacked outputs per thread (proven: VGPR 56, ~30us).
// =====================================================================
__global__ __launch_bounds__(256) void conv_silu_kernel(
    const bf16_t* __restrict__ zx,
    const float* __restrict__ wA, const float* __restrict__ bA,
    const float* __restrict__ wB, const float* __restrict__ bB,
    bf16_t* __restrict__ out)
{
    const int idx = blockIdx.x * 256 + threadIdx.x;   // < 8192*80
    const int cb = idx % CBLK;
    const int pc = idx / CBLK;         // (b,h4,w) column id, < 8192
    const int c0 = cb * 8;
    const int ww = pc & (WW - 1);
    const int h4 = (pc >> 7) & 15;
    const int b  = pc >> 11;
    const int hbase = h4 * 4;
    const float* wp = (b < 2) ? wA : wB;
    const float* bp = (b < 2) ? bA : bB;

    float w[72];
    const float4* wsrc = (const float4*)(wp + c0 * 9);
    #pragma unroll
    for (int i = 0; i < 18; ++i) ((float4*)w)[i] = wsrc[i];

    float acc[4][8];
    {
        float4 bv0 = *(const float4*)(bp + c0);
        float4 bv1 = *(const float4*)(bp + c0 + 4);
        #pragma unroll
        for (int o = 0; o < 4; ++o) {
            acc[o][0] = bv0.x; acc[o][1] = bv0.y; acc[o][2] = bv0.z; acc[o][3] = bv0.w;
            acc[o][4] = bv1.x; acc[o][5] = bv1.y; acc[o][6] = bv1.z; acc[o][7] = bv1.w;
        }
    }

    const bf16_t* base = zx + (size_t)b * LSEQ * DPROJ + DINNER + c0;
    #pragma unroll
    for (int ri = 0; ri < 6; ++ri) {           // input rows hbase-1 .. hbase+4
        const int hi = hbase + ri - 1;
        const bool hok = (unsigned)hi < (unsigned)HH;
        float cur[3][8];
        #pragma unroll
        for (int kj = 0; kj < 3; ++kj) {
            const int wi = ww + kj - 1;
            if (hok && (unsigned)wi < (unsigned)WW) {
                const ushort8v v = *(const ushort8v*)(base + (size_t)(hi * WW + wi) * DPROJ);
                #pragma unroll
                for (int q = 0; q < 8; ++q) cur[kj][q] = bf2f(v[q]);
            } else {
                #pragma unroll
                for (int q = 0; q < 8; ++q) cur[kj][q] = 0.f;
            }
        }
        #pragma unroll
        for (int o = 0; o < 4; ++o) {
            const int ki = ri - o;             // tap row for output o
            if (ki >= 0 && ki < 3) {
                #pragma unroll
                for (int kj = 0; kj < 3; ++kj)
                    #pragma unroll
                    for (int q = 0; q < 8; ++q)
                        acc[o][q] += cur[kj][q] * w[q * 9 + ki * 3 + kj];
            }
        }
    }

    #pragma unroll
    for (int o = 0; o < 4; ++o) {
        const int t = b * LSEQ + (hbase + o) * WW + ww;
        ushort8v ov;
        #pragma unroll
        for (int q = 0; q < 8; ++q) {
            const float s = acc[o][q] / (1.f + expf(-acc[o][q]));   // silu
            ov[q] = f2bf(s);
        }
        *(ushort8v*)(out + (size_t)t * CONVD + c0) = ov;
    }
}

// =====================================================================
// KV partials (dt fused): KVp[chunk][(b*8+h)*4096 + s*64 + p]
// =====================================================================
__global__ __launch_bounds__(128) void kv_part_kernel(
    const bf16_t* __restrict__ xconv, const bf16_t* __restrict__ zx,
    const float* __restrict__ dt_bias,
    const float* __restrict__ A_log, float* __restrict__ KVp)
{
    const int h = blockIdx.y, b = blockIdx.z, chunk = blockIdx.x;
    const int tid = threadIdx.x;
    const int w = tid >> 6, lane = tid & 63;
    __shared__ float lds[2 * 4352];
    float* Bt = lds + w * 4352;
    float* Xt = Bt + 2176;
    const float eA = expf(A_log[h]);
    const float dtb = dt_bias[h];
    const int s4  = (lane & 15) * 4;
    const int p16 = (lane >> 4) * 16;
    const int r    = lane & 31;
    const int part = lane >> 5;

    float acc[4][16];
    #pragma unroll
    for (int i = 0; i < 4; ++i)
        #pragma unroll
        for (int j = 0; j < 16; ++j) acc[i][j] = 0.f;

    const int l0 = b * LSEQ + chunk * 256;

    for (int t = 0; t < 8; t += 2) {
        const int row = l0 + (t + w) * 32 + r;
        const bf16_t* src = xconv + (size_t)row * CONVD + (part ? h * 64 : DINNER);
        float scale = 1.f;
        if (part) {
            const float v = bf2f(zx[(size_t)row * DPROJ + (DINNER + CONVD) + h]) + dtb;
            const float sp = (v > 0.f) ? (v + log1pf(expf(-v))) : log1pf(expf(v));
            scale = sp * eA;
        }
        float* dst = part ? &Xt[r * 68] : &Bt[r * 68];
        #pragma unroll
        for (int j = 0; j < 8; ++j) {
            ushort8v v = *(const ushort8v*)(src + j * 8);
            f32x4 lo = {bf2f(v[0]) * scale, bf2f(v[1]) * scale,
                        bf2f(v[2]) * scale, bf2f(v[3]) * scale};
            f32x4 hi = {bf2f(v[4]) * scale, bf2f(v[5]) * scale,
                        bf2f(v[6]) * scale, bf2f(v[7]) * scale};
            *(f32x4*)&dst[j * 8]     = lo;
            *(f32x4*)&dst[j * 8 + 4] = hi;
        }
        __syncthreads();
        #pragma unroll 4
        for (int rr = 0; rr < 32; ++rr) {
            const f32x4 bv = *(const f32x4*)&Bt[rr * 68 + s4];
            #pragma unroll
            for (int q = 0; q < 4; ++q) {
                const f32x4 xv = *(const f32x4*)&Xt[rr * 68 + p16 + q * 4];
                #pragma unroll
                for (int si = 0; si < 4; ++si)
                    #pragma unroll
                    for (int k = 0; k < 4; ++k)
                        acc[si][q * 4 + k] += bv[si] * xv[k];
            }
        }
        __syncthreads();
    }

    if (w == 0) {
        #pragma unroll
        for (int si = 0; si < 4; ++si)
            #pragma unroll
            for (int q = 0; q < 4; ++q)
                *(f32x4*)&lds[(s4 + si) * 68 + p16 + q * 4] =
                    (f32x4){acc[si][q*4], acc[si][q*4+1], acc[si][q*4+2], acc[si][q*4+3]};
    }
    __syncthreads();
    if (w == 1) {
        float* dst = KVp + ((size_t)chunk * (NB * NH) + (b * NH + h)) * 4096;
        #pragma unroll
        for (int si = 0; si < 4; ++si)
            #pragma unroll
            for (int q = 0; q < 4; ++q) {
                const f32x4 o = *(const f32x4*)&lds[(s4 + si) * 68 + p16 + q * 4];
                f32x4 v = {acc[si][q*4] + o[0], acc[si][q*4+1] + o[1],
                           acc[si][q*4+2] + o[2], acc[si][q*4+3] + o[3]};
                *(f32x4*)&dst[(s4 + si) * 64 + p16 + q * 4] = v;
            }
    }
}

// =====================================================================
// KVT[b][h*64+p][s] (bf16) = sum_chunk KVp[chunk][(b*8+h)*4096+s*64+p]
// =====================================================================
__global__ __launch_bounds__(256) void kv_reduce_T_kernel(
    const float* __restrict__ KVp, bf16_t* __restrict__ KVT)
{
    const int idx = blockIdx.x * 256 + threadIdx.x;   // < 131072
    float s = 0.f;
    #pragma unroll
    for (int c = 0; c < KVCH; ++c) s += KVp[(size_t)c * 131072 + idx];
    const int bh = idx >> 12;          // b*8+h
    const int ss = (idx >> 6) & 63;
    const int p  = idx & 63;
    KVT[((size_t)(bh * 64 + p)) * 64 + ss] = f2bf(s);
}

// =====================================================================
// LN + gate: y = Yattn + x*Dv -> LayerNorm(512) -> *g+b -> *z -> ybuf
// =====================================================================
__global__ __launch_bounds__(256) void ln_gate_kernel(
    const bf16_t* __restrict__ Yattn, const bf16_t* __restrict__ xconv,
    const bf16_t* __restrict__ zx,
    const float* __restrict__ DA, const float* __restrict__ DB,
    const float* __restrict__ ln_g, const float* __restrict__ ln_b,
    bf16_t* __restrict__ ybuf)
{
    const int w = threadIdx.x >> 6, lane = threadIdx.x & 63;
    const int c0 = lane * 8;
    const int h = lane >> 3;
    float g[8], be[8];
    *(float4*)&g[0]  = *(const float4*)&ln_g[c0];
    *(float4*)&g[4]  = *(const float4*)&ln_g[c0 + 4];
    *(float4*)&be[0] = *(const float4*)&ln_b[c0];
    *(float4*)&be[4] = *(const float4*)&ln_b[c0 + 4];
    const int row0 = (blockIdx.x * 4 + w) * 4;

    for (int i = 0; i < 4; ++i) {
        const int row = row0 + i;
        const int b = row >> 13;
        const float Dv = (b < 2) ? DA[h] : DB[h];
        ushort8v yv = *(const ushort8v*)(Yattn + (size_t)row * DINNER + c0);
        ushort8v xv = *(const ushort8v*)(xconv + (size_t)row * CONVD + c0);
        float y[8];
        float s1 = 0.f, s2 = 0.f;
        #pragma unroll
        for (int q = 0; q < 8; ++q) {
            y[q] = bf2f(yv[q]) + bf2f(xv[q]) * Dv;
            s1 += y[q]; s2 += y[q] * y[q];
        }
        #pragma unroll
        for (int off = 32; off > 0; off >>= 1) {
            s1 += __shfl_xor(s1, off, 64);
            s2 += __shfl_xor(s2, off, 64);
        }
        const float mu = s1 * (1.f / 512.f);
        const float var = s2 * (1.f / 512.f) - mu * mu;
        const float rstd = rsqrtf(var + 1e-5f);
        ushort8v zv = *(const ushort8v*)(zx + (size_t)row * DPROJ + c0);
        ushort8v o;
        #pragma unroll
        for (int q = 0; q < 8; ++q)
            o[q] = f2bf(((y[q] - mu) * rstd * g[q] + be[q]) * bf2f(zv[q]));
        *(ushort8v*)(ybuf + (size_t)row * DINNER + c0) = o;
    }
}

// =====================================================================
extern "C" void kernel_launch(void* const* d_in, const int* in_sizes, int n_in,
                              void* d_out, int out_size, void* d_ws, size_t ws_size,
                              hipStream_t stream)
{
    const float* u        = (const float*)d_in[0];
    const float* W_in     = (const float*)d_in[3];
    const float* W_st     = (const float*)d_in[4];
    const float* conv_l_w = (const float*)d_in[5];
    const float* conv_l_b = (const float*)d_in[6];
    const float* conv_r_w = (const float*)d_in[7];
    const float* conv_r_b = (const float*)d_in[8];
    const float* conv_w   = (const float*)d_in[9];
    const float* conv_b   = (const float*)d_in[10];
    const float* dt_bias  = (const float*)d_in[11];
    const float* A_log    = (const float*)d_in[12];
    const float* D_l      = (const float*)d_in[13];
    const float* D_r      = (const float*)d_in[14];
    const float* Dp       = (const float*)d_in[15];
    const float* ln_g     = (const float*)d_in[16];
    const float* ln_b     = (const float*)d_in[17];
    const float* W_out    = (const float*)d_in[18];
    float* out = (float*)d_out;

    // ---- workspace layout: ~205 MB (KVp aliases ubf; KVT bf16; Yattn bf16) ----
    char* ws = (char*)d_ws;
    const size_t ZX_B    = (size_t)MROWS * DPROJ * 2;    //  76,021,760
    const size_t XCONV_B = (size_t)MROWS * CONVD * 2;    //  41,943,040
    const size_t YBUF_B  = (size_t)MROWS * DINNER * 2;   //  33,554,432
    const size_t DT_B    = (size_t)MROWS * NH * 4;       //   1,048,576 (unused; layout stability)
    const size_t KVT_B   = (size_t)NB * DINNER * 64 * 2; //     262,144
    const size_t UBF_B   = (size_t)MROWS * DMODEL * 2;   //  16,777,216 (== KVCH*131072*4)
    const size_t WIN_B   = (size_t)1280 * DMODEL * 2;
    const size_t WST_B   = (size_t)1280 * DINNER * 2;
    const size_t WOUT_B  = (size_t)256 * DINNER * 2;
    bf16_t* zx    = (bf16_t*)(ws);
    bf16_t* xconv = (bf16_t*)(ws + ZX_B);
    bf16_t* ybuf  = (bf16_t*)(ws + ZX_B + XCONV_B);
    bf16_t* KVT   = (bf16_t*)(ws + ZX_B + XCONV_B + YBUF_B + DT_B);
    bf16_t* ubf   = (bf16_t*)(ws + ZX_B + XCONV_B + YBUF_B + DT_B + KVT_B);
    float*  KVp   = (float*) (ws + ZX_B + XCONV_B + YBUF_B + DT_B + KVT_B);  // alias (ubf dead after gemm1)
    bf16_t* WinP  = (bf16_t*)(ws + ZX_B + XCONV_B + YBUF_B + DT_B + KVT_B + UBF_B);
    bf16_t* WstP  = (bf16_t*)(ws + ZX_B + XCONV_B + YBUF_B + DT_B + KVT_B + UBF_B + WIN_B);
    bf16_t* WoutP = (bf16_t*)(ws + ZX_B + XCONV_B + YBUF_B + DT_B + KVT_B + UBF_B + WIN_B + WST_B);
    bf16_t* Yattn = (bf16_t*)(ws + ZX_B + XCONV_B + YBUF_B + DT_B + KVT_B + UBF_B + WIN_B + WST_B + WOUT_B);

    const dim3 gemmGridP(10, MROWS / 256);        // Npad=1280, 1280 blocks (%8==0)
    const dim3 gemmGridO(2,  MROWS / 128, 1);     // out-proj on bt: 512 blocks
    const dim3 ymmGrid(4, LSEQ / 128, NB);        // N=512, per-batch
    const dim3 kvGrid(KVCH, NH, NB);
    const int convGrid = (MROWS / 4) * CBLK / 256; // 2560
    const int lnGrid = MROWS / 16;                 // 2048

    // ---- one-time conversions ----
    cvt_bf16_kernel<<<(MROWS * DMODEL / 4 + 255) / 256, 256, 0, stream>>>(u, ubf, MROWS * DMODEL);
    wpad_kernel<<<(1280 * DMODEL + 255) / 256, 256, 0, stream>>>(W_in, WinP, DPROJ, 1280, DMODEL);
    wpad_kernel<<<(1280 * DINNER + 255) / 256, 256, 0, stream>>>(W_st, WstP, DPROJ, 1280, DINNER);
    wpad_kernel<<<(256 * DINNER + 255) / 256, 256, 0, stream>>>(W_out, WoutP, DMODEL, 256, DINNER);

    // ---------------- pass 1 ----------------
    gemm_mfma_big<bf16_t><<<gemmGridP, 512, 0, stream>>>(
        ubf, DMODEL, WinP, DMODEL, zx, DPROJ, MROWS, DPROJ, DMODEL);
    conv_silu_kernel<<<convGrid, 256, 0, stream>>>(
        zx, conv_l_w, conv_l_b, conv_r_w, conv_r_b, xconv);
    kv_part_kernel<<<kvGrid, 128, 0, stream>>>(xconv, zx, dt_bias, A_log, KVp);
    kv_reduce_T_kernel<<<131072 / 256, 256, 0, stream>>>(KVp, KVT);
    gemm_mfma_bt<bf16_t><<<ymmGrid, 256, 0, stream>>>(
        xconv + DINNER + DSTATE, CONVD, (size_t)LSEQ * CONVD,
        KVT, 64, (size_t)DINNER * 64,
        Yattn, DINNER, (size_t)LSEQ * DINNER, LSEQ, DINNER, 64);
    ln_gate_kernel<<<lnGrid, 256, 0, stream>>>(
        Yattn, xconv, zx, D_l, D_r, ln_g, ln_b, ybuf);

    // ---------------- pass 2 ----------------
    gemm_mfma_big<bf16_t><<<gemmGridP, 512, 0, stream>>>(
        ybuf, DINNER, WstP, DINNER, zx, DPROJ, MROWS, DPROJ, DINNER);
    conv_silu_kernel<<<convGrid, 256, 0, stream>>>(
        zx, conv_w, conv_b, conv_w, conv_b, xconv);
    kv_part_kernel<<<kvGrid, 128, 0, stream>>>(xconv, zx, dt_bias, A_log, KVp);
    kv_reduce_T_kernel<<<131072 / 256, 256, 0, stream>>>(KVp, KVT);
    gemm_mfma_bt<bf16_t><<<ymmGrid, 256, 0, stream>>>(
        xconv + DINNER + DSTATE, CONVD, (size_t)LSEQ * CONVD,
        KVT, 64, (size_t)DINNER * 64,
        Yattn, DINNER, (size_t)LSEQ * DINNER, LSEQ, DINNER, 64);
    ln_gate_kernel<<<lnGrid, 256, 0, stream>>>(
        Yattn, xconv, zx, Dp, Dp, ln_g, ln_b, ybuf);

    // ---------------- output projection (128-tile bt: 512 blocks) ----------------
    gemm_mfma_bt<float><<<gemmGridO, 256, 0, stream>>>(
        ybuf, DINNER, 0, WoutP, DINNER, 0, out, DMODEL, 0, MROWS, DMODEL, DINNER);
}